// Round 11
// baseline (184.522 us; speedup 1.0000x reference)
//
#include <hip/hip_runtime.h>

// LBP uniform P=8 R=1 on (32,3,512,512) f32, zero-padded borders.
// R7: software-pipelined full-row wave streaming.
// Evidence trail: R3(51us)=R6(51us) despite 2x occupancy delta -> residency
// not the limiter. FETCH/WRITE compulsory everywhere -> traffic not the
// limiter. No pipe >40% busy -> the cap is outstanding-load duty cycle:
// one-shot threads have loads in flight only ~40% of wave lifetime
// (Little's law needs ~9KB/CU outstanding continuously for 6.3 TB/s).
// R5's pipeline attempt failed because per-load OOB branches let the
// compiler sink loads (VGPR=40 proved it) and 32B-stride lanes broke
// coalescing (WRITE 130MB). R7 fixes both:
//   - wave owns a full 512-col row; lane i owns cols 4i..4i+3 (chunk A)
//     and 256+4i..256+4i+3 (chunk B): every load & store is a perfectly
//     lane-contiguous dwordx4. ZERO scalar edge loads: column halo comes
//     from 4 shfl + 2 broadcast-shfl per row; lane0/lane63 are the true
//     image borders (exact zero pad).
//   - branchless OOB: clamped row address + wave-uniform row-scale
//     (rs = in-image ? 255 : 0) folded into the quantize multiply. No
//     control flow anywhere in the loop -> loads hoist freely.
//   - rolling 3-row register window over an 8-row strip (read amp 1.25x);
//     loads for row p+2 issued BEFORE compute of row p -> every wave has
//     loads outstanding ~always. Raw double-buffer slots indexed by (p&1),
//     prep ring by %3 -- all compile-time constants (fully unrolled).
//   - neighbors skip floorf (floor(t)>=q <=> t>=q for integer q): bit-exact.
//   - 6144 waves == exactly one resident set at launch_bounds(256,6);
//     XCD-contiguous swizzle keeps vertically-adjacent strips (shared halo
//     rows) on the same XCD L2.

#define LBP_H 512
#define LBP_W 512
#define NPLANES 96           // 32 * 3
#define HSTRIP 8             // output rows per wave

typedef float f32x4 __attribute__((ext_vector_type(4)));

struct Row { float ea[6]; float eb[6]; };   // extended windows for chunks A,B

__device__ __forceinline__ float lbp_pix(const float* t, const float* m,
                                         const float* b, int c) {
    const float q = floorf(m[c + 1]);        // center, integer-valued
    // circular order: (-1,-1),(-1,0),(-1,1),(0,1),(1,1),(1,0),(1,-1),(0,-1)
    unsigned msk = 0u;
    msk |= (t[c    ] >= q) ?   1u : 0u;
    msk |= (t[c + 1] >= q) ?   2u : 0u;
    msk |= (t[c + 2] >= q) ?   4u : 0u;
    msk |= (m[c + 2] >= q) ?   8u : 0u;
    msk |= (b[c + 2] >= q) ?  16u : 0u;
    msk |= (b[c + 1] >= q) ?  32u : 0u;
    msk |= (b[c    ] >= q) ?  64u : 0u;
    msk |= (m[c    ] >= q) ? 128u : 0u;
    const unsigned rot = ((msk >> 1) | (msk << 7)) & 255u;
    const int trans = __popc(msk ^ rot);
    const int val = (trans <= 2) ? __popc(msk) : 9;
    return (float)val * (1.0f / 255.0f);
}

__global__ __launch_bounds__(256, 6) void lbp_kernel(const float* __restrict__ x,
                                                     float* __restrict__ out) {
    // XCD-contiguous swizzle: 1536 blocks, 8 XCDs -> 192 consecutive
    // work-units per XCD (vertical halo neighbors share an L2).
    const int bid = blockIdx.x;
    const int swz = (bid & 7) * 192 + (bid >> 3);
    const int wid  = (swz << 2) + (threadIdx.x >> 6);   // global wave id
    const int lane = threadIdx.x & 63;
    const int plane = wid >> 6;          // 0..95
    const int strip = wid & 63;          // 0..63
    const int r0    = strip << 3;        // first output row

    const float* base  = x   + (size_t)plane * (LBP_H * LBP_W) + (lane << 2);
    float*       obase = out + (size_t)plane * (LBP_H * LBP_W) + (lane << 2);

    f32x4 rawA[2], rawB[2];
    float rs[2];
    Row pr[3];

    // branchless clamped row load into double-buffer slot
    auto LOADR = [&](int gr, int slot) {
        const int gc = gr < 0 ? 0 : (gr > LBP_H - 1 ? LBP_H - 1 : gr);
        const float* rp = base + (size_t)gc * LBP_W;
        rawA[slot] = *(const f32x4*)rp;
        rawB[slot] = *(const f32x4*)(rp + 256);
        rs[slot]   = ((unsigned)gr < LBP_H) ? 255.0f : 0.0f;  // wave-uniform
    };
    // quantize-scale + column halo via shuffles
    auto PREPR = [&](int slot, Row& w) {
        const float s = rs[slot];
        const f32x4 A = rawA[slot];
        const f32x4 B = rawB[slot];
        const float a0 = A.x * s, a1 = A.y * s, a2 = A.z * s, a3 = A.w * s;
        const float b0 = B.x * s, b1 = B.y * s, b2 = B.z * s, b3 = B.w * s;
        const float la = __shfl_up(a3, 1);     // lane i-1 col 4i-1
        const float ra = __shfl_down(a0, 1);   // lane i+1 col 4i+4
        const float lb = __shfl_up(b3, 1);
        const float rb = __shfl_down(b0, 1);
        const float a3_63 = __shfl(a3, 63);    // col 255 (for chunk B lane 0)
        const float b0_0  = __shfl(b0, 0);     // col 256 (for chunk A lane 63)
        w.ea[0] = (lane == 0)  ? 0.0f  : la;   // true left image border
        w.ea[1] = a0; w.ea[2] = a1; w.ea[3] = a2; w.ea[4] = a3;
        w.ea[5] = (lane == 63) ? b0_0  : ra;
        w.eb[0] = (lane == 0)  ? a3_63 : lb;
        w.eb[1] = b0; w.eb[2] = b1; w.eb[3] = b2; w.eb[4] = b3;
        w.eb[5] = (lane == 63) ? 0.0f  : rb;   // true right image border
    };

    // ---- prologue: rows r0-1, r0, r0+1; keep 2 loads always in flight ----
    LOADR(r0 - 1, 0);
    LOADR(r0,     1);
    PREPR(0, pr[0]);                 // row r0-1
    LOADR(r0 + 1, 0);                // slot0 free again
    PREPR(1, pr[1]);                 // row r0

    // ---- main loop: compute row r0+p from pr[p%3], pr[(p+1)%3], pr[(p+2)%3]
#pragma unroll
    for (int p = 0; p < HSTRIP; ++p) {
        const int ls = p & 1;        // slot holding row r0+p+1
        const int ns = ls ^ 1;
        if (p + 2 <= HSTRIP) LOADR(r0 + p + 2, ns);   // issue ahead of wait
        PREPR(ls, pr[(p + 2) % 3]);                   // prep row r0+p+1

        const float* tA = pr[p % 3].ea;
        const float* mA = pr[(p + 1) % 3].ea;
        const float* bA = pr[(p + 2) % 3].ea;
        const float* tB = pr[p % 3].eb;
        const float* mB = pr[(p + 1) % 3].eb;
        const float* bB = pr[(p + 2) % 3].eb;

        f32x4 oA, oB;
#pragma unroll
        for (int c = 0; c < 4; ++c) {
            oA[c] = lbp_pix(tA, mA, bA, c);
            oB[c] = lbp_pix(tB, mB, bB, c);
        }
        float* op = obase + (size_t)(r0 + p) * LBP_W;
        __builtin_nontemporal_store(oA, (f32x4*)op);
        __builtin_nontemporal_store(oB, (f32x4*)(op + 256));
    }
}

extern "C" void kernel_launch(void* const* d_in, const int* in_sizes, int n_in,
                              void* d_out, int out_size, void* d_ws, size_t ws_size,
                              hipStream_t stream) {
    const float* x = (const float*)d_in[0];
    float* out = (float*)d_out;
    // 96 planes x 64 strips = 6144 waves = 1536 blocks of 256 threads
    const int blocks = NPLANES * 64 / 4;
    lbp_kernel<<<blocks, 256, 0, stream>>>(x, out);
}

// Round 12
// 176.345 us; speedup vs baseline: 1.0464x; 1.0464x over previous
//
#include <hip/hip_runtime.h>

// LBP uniform P=8 R=1 on (32,3,512,512) f32, zero-padded borders.
// R8: one-shot + shuffle halo. Evidence: R3(51us)=R6(51us) one-shot beat
// every pipelined variant (R4 68, R5 84, R7 67.5); R7's VGPR=40 proved the
// compiler collapses source-level pipelines (3rd failure -> abandoned).
// Last unfalsified co-limiter of the 51us floor: VMEM instruction/TA
// pressure from scalar edge gathers (2/3 of VMEM ops in R3/R6, 16
// cache-line touches per wave-gather). R8 keeps the proven one-shot shape
// but goes gather-free:
//   - wave owns a full 512-col row pair; lane i owns cols 4i..4i+3 (A) and
//     256+4i..256+4i+3 (B). All 8 loads + 4 stores are lane-contiguous
//     dwordx4. Column halo entirely via shuffles (R7-verified mapping:
//     absmax=0): lane0/63 are true image borders.
//   - 16 px/thread (2 rows x 8 cols): 4 input rows x 2 chunks, clamped
//     row addresses + wave-uniform scale (rs = in-image ? 255 : 0).
//   - neighbors skip floorf (floor(t)>=q <=> t>=q, q integer): bit-exact.
//   - XCD-contiguous swizzle: 6144 blocks = 8 x 768 (bijective), vertical
//     halo neighbors share an XCD L2.

#define LBP_H 512
#define LBP_W 512
#define NPLANES 96           // 32 * 3

typedef float f32x4 __attribute__((ext_vector_type(4)));

__device__ __forceinline__ float lbp_pix(const float* t, const float* m,
                                         const float* b, int c) {
    const float q = floorf(m[c + 1]);        // center, integer-valued
    // circular order: (-1,-1),(-1,0),(-1,1),(0,1),(1,1),(1,0),(1,-1),(0,-1)
    unsigned msk = 0u;
    msk |= (t[c    ] >= q) ?   1u : 0u;
    msk |= (t[c + 1] >= q) ?   2u : 0u;
    msk |= (t[c + 2] >= q) ?   4u : 0u;
    msk |= (m[c + 2] >= q) ?   8u : 0u;
    msk |= (b[c + 2] >= q) ?  16u : 0u;
    msk |= (b[c + 1] >= q) ?  32u : 0u;
    msk |= (b[c    ] >= q) ?  64u : 0u;
    msk |= (m[c    ] >= q) ? 128u : 0u;
    const unsigned rot = ((msk >> 1) | (msk << 7)) & 255u;
    const int trans = __popc(msk ^ rot);
    const int val = (trans <= 2) ? __popc(msk) : 9;
    return (float)val * (1.0f / 255.0f);
}

__global__ __launch_bounds__(256, 6) void lbp_kernel(const float* __restrict__ x,
                                                     float* __restrict__ out) {
    // XCD-contiguous swizzle: 6144 blocks, 8 XCDs -> 768 consecutive
    // work-units per XCD.
    const int bid = blockIdx.x;
    const int swz = (bid & 7) * 768 + (bid >> 3);
    const int wid  = (swz << 2) + (threadIdx.x >> 6);   // global wave id
    const int lane = threadIdx.x & 63;
    const int plane = wid >> 8;          // 0..95
    const int strip = wid & 255;         // 0..255 (2 output rows each)
    const int r0    = strip << 1;        // first output row

    const float* base  = x   + (size_t)plane * (LBP_H * LBP_W) + (lane << 2);
    float*       obase = out + (size_t)plane * (LBP_H * LBP_W) + (lane << 2);

    // ---- phase 1: ALL 8 coalesced loads, back-to-back, clamped rows ----
    f32x4 A[4], B[4];
    float sc[4];
#pragma unroll
    for (int r = 0; r < 4; ++r) {
        const int gr = r0 - 1 + r;                       // input row
        const int gc = gr < 0 ? 0 : (gr > LBP_H - 1 ? LBP_H - 1 : gr);
        const float* rp = base + (size_t)gc * LBP_W;
        A[r] = *(const f32x4*)rp;
        B[r] = *(const f32x4*)(rp + 256);
        sc[r] = ((unsigned)gr < LBP_H) ? 255.0f : 0.0f;  // wave-uniform
    }

    // ---- phase 2: quantize-scale + shuffle halo (R7-verified mapping) ----
    // wA[r]: cols 4i-1 .. 4i+4 ; wB[r]: cols 256+4i-1 .. 256+4i+4
    float wA[4][6], wB[4][6];
#pragma unroll
    for (int r = 0; r < 4; ++r) {
        const float s = sc[r];
        const float a0 = A[r].x * s, a1 = A[r].y * s,
                    a2 = A[r].z * s, a3 = A[r].w * s;
        const float b0 = B[r].x * s, b1 = B[r].y * s,
                    b2 = B[r].z * s, b3 = B[r].w * s;
        const float la = __shfl_up(a3, 1);     // lane i-1 col 4i-1
        const float ra = __shfl_down(a0, 1);   // lane i+1 col 4i+4
        const float lb = __shfl_up(b3, 1);
        const float rb = __shfl_down(b0, 1);
        const float a3_63 = __shfl(a3, 63);    // col 255 (chunk B lane 0 left)
        const float b0_0  = __shfl(b0, 0);     // col 256 (chunk A lane 63 right)
        wA[r][0] = (lane == 0)  ? 0.0f  : la;  // true left image border
        wA[r][1] = a0; wA[r][2] = a1; wA[r][3] = a2; wA[r][4] = a3;
        wA[r][5] = (lane == 63) ? b0_0  : ra;
        wB[r][0] = (lane == 0)  ? a3_63 : lb;
        wB[r][1] = b0; wB[r][2] = b1; wB[r][3] = b2; wB[r][4] = b3;
        wB[r][5] = (lane == 63) ? 0.0f  : rb;  // true right image border
    }

    // ---- phase 3: 16 LBP codes, 4 coalesced nt stores ----
#pragma unroll
    for (int p = 0; p < 2; ++p) {             // output row r0+p
        f32x4 oA, oB;
#pragma unroll
        for (int c = 0; c < 4; ++c) {
            oA[c] = lbp_pix(wA[p], wA[p + 1], wA[p + 2], c);
            oB[c] = lbp_pix(wB[p], wB[p + 1], wB[p + 2], c);
        }
        float* op = obase + (size_t)(r0 + p) * LBP_W;
        __builtin_nontemporal_store(oA, (f32x4*)op);
        __builtin_nontemporal_store(oB, (f32x4*)(op + 256));
    }
}

extern "C" void kernel_launch(void* const* d_in, const int* in_sizes, int n_in,
                              void* d_out, int out_size, void* d_ws, size_t ws_size,
                              hipStream_t stream) {
    const float* x = (const float*)d_in[0];
    float* out = (float*)d_out;
    // 96 planes x 256 strips = 24576 waves = 6144 blocks of 256 threads
    const int blocks = NPLANES * 256 / 4;
    lbp_kernel<<<blocks, 256, 0, stream>>>(x, out);
}